// Round 18
// baseline (125.113 us; speedup 1.0000x reference)
//
#include <hip/hip_runtime.h>

typedef __attribute__((ext_vector_type(8))) short bf16x8;
typedef __attribute__((ext_vector_type(16))) float f32x16;
typedef __attribute__((ext_vector_type(2))) float f32x2;
typedef __attribute__((ext_vector_type(8))) unsigned short u16x8;
typedef __attribute__((ext_vector_type(4))) unsigned short u16x4;
typedef __attribute__((ext_vector_type(4))) unsigned int u32x4;
typedef __attribute__((ext_vector_type(2))) unsigned int u32x2;

#define NB 8
#define EH 64
#define NS 4096
#define SCALE_L2E 0.1803368801111204f  /* 0.125 * log2(e) */

static __device__ __forceinline__ unsigned short f2bf(float f) {
  union { float f; unsigned int u; } a;
  a.f = f;
  unsigned int u = a.u;
  unsigned int lsb = (u >> 16) & 1u;
  u += 0x7fffu + lsb;  // RNE
  return (unsigned short)(u >> 16);
}

static __device__ __forceinline__ unsigned int cvtpk(float a, float b) {
  unsigned int r;
  asm("v_cvt_pk_bf16_f32 %0, %1, %2" : "=v"(r) : "v"(a), "v"(b));
  return r;
}

// raw single-instruction exp2 WITH compiler hazard handling (R14-proven).
static __device__ __forceinline__ float fexp2(float x) {
#if __has_builtin(__builtin_amdgcn_exp2f)
  return __builtin_amdgcn_exp2f(x);
#else
  return exp2f(x);
#endif
}

// 1-bit signed bitfield extract: returns 0 or -1 (v_bfe_i32, 1 op)
static __device__ __forceinline__ int sbfe1(unsigned int v, int off) {
#if __has_builtin(__builtin_amdgcn_sbfe)
  return __builtin_amdgcn_sbfe((int)v, off, 1);
#else
  return ((int)(v << (31 - off))) >> 31;
#endif
}

// cross-half (lane ^ 32) sum via v_permlane32_swap
static __device__ __forceinline__ float xsum32(float x) {
  u32x2 r = __builtin_amdgcn_permlane32_swap(__float_as_uint(x), __float_as_uint(x), false, false);
  return __uint_as_float(r[0]) + __uint_as_float(r[1]);
}

static __device__ __forceinline__ void gl_lds16(const void* g, void* l) {
  __builtin_amdgcn_global_load_lds(
      (const __attribute__((address_space(1))) unsigned int*)g,
      (__attribute__((address_space(3))) unsigned int*)l, 16, 0, 0);
}

// ---------------- fused prepass (one launch):
//   bid <  4096 : mask (Nk,Nq) -> bit-packed (Nk/32, Nq), inline dtype detect
//   4096..4607  : K transpose (B,E,N) f32 -> (B,N,E) bf16
//   4608..5119  : V convert   (B,E,N) f32 -> bf16 (layout kept)
__global__ __launch_bounds__(256) void k_pre(const float* __restrict__ Kf,
                                             const float* __restrict__ Vf,
                                             const unsigned char* __restrict__ Mp,
                                             unsigned short* __restrict__ Kb,
                                             unsigned short* __restrict__ Vb,
                                             unsigned int* __restrict__ Bits) {
  const int bid = blockIdx.x;
  const int t = threadIdx.x;
  if (bid < 4096) {
    __shared__ unsigned char Ts[64][80];
    __shared__ int sfl;
    const int q0 = (bid & 63) << 6;
    const int ky = bid >> 6;
    const int k0 = ky << 6;
    if (t == 0) sfl = 1;
    __syncthreads();
    {
      const unsigned int w0 = reinterpret_cast<const unsigned int*>(Mp)[t];
      if (!(w0 == 0u || w0 == 1u || w0 == 0x3F800000u)) sfl = 0;  // benign race
    }
    __syncthreads();
    const int wide = sfl;
    const int r = t >> 2, cs = t & 3;
    if (!wide) {
      int4 v = *reinterpret_cast<const int4*>(Mp + (size_t)(k0 + r) * NS + q0 + cs * 16);
      *reinterpret_cast<int4*>(&Ts[r][cs * 16]) = v;
    } else {
      const unsigned int* Mw =
          reinterpret_cast<const unsigned int*>(Mp) + (size_t)(k0 + r) * NS + q0 + cs * 16;
      unsigned char tmp[16];
#pragma unroll
      for (int j = 0; j < 16; ++j) tmp[j] = (unsigned char)(Mw[j] != 0u);
      *reinterpret_cast<int4*>(&Ts[r][cs * 16]) = *reinterpret_cast<const int4*>(tmp);
    }
    __syncthreads();
    const int w = t >> 6, lane = t & 63;
#pragma unroll
    for (int i = 0; i < 16; ++i) {
      const int q = (w << 4) + i;
      unsigned long long bm = __ballot(Ts[lane][q] != 0);
      if (lane == 0) {
        Bits[(size_t)(2 * ky) * NS + q0 + q] = (unsigned int)bm;
        Bits[(size_t)(2 * ky + 1) * NS + q0 + q] = (unsigned int)(bm >> 32);
      }
    }
  } else if (bid < 4608) {
    __shared__ float T[64][69];
    const int id = bid - 4096;
    const int b = id >> 6;
    const int n0 = (id & 63) << 6;
    const float* Xb = Kf + (size_t)b * EH * NS;
    unsigned short* Yb = Kb + (size_t)b * NS * EH;
    const int er = t >> 4;
    const int n4 = (t & 15) << 2;
#pragma unroll
    for (int p = 0; p < 4; ++p) {
      const int e = er + (p << 4);
      const float4 v = *reinterpret_cast<const float4*>(Xb + (size_t)e * NS + n0 + n4);
      T[e][n4] = v.x; T[e][n4 + 1] = v.y; T[e][n4 + 2] = v.z; T[e][n4 + 3] = v.w;
    }
    __syncthreads();
    const int n = t >> 2;
    const int e0 = (t & 3) << 4;
    u16x8 o0, o1;
#pragma unroll
    for (int j = 0; j < 8; ++j) o0[j] = f2bf(T[e0 + j][n]);
#pragma unroll
    for (int j = 0; j < 8; ++j) o1[j] = f2bf(T[e0 + 8 + j][n]);
    *reinterpret_cast<u16x8*>(Yb + (size_t)(n0 + n) * EH + e0) = o0;
    *reinterpret_cast<u16x8*>(Yb + (size_t)(n0 + n) * EH + e0 + 8) = o1;
  } else {
    const int id = bid - 4608;
    const size_t base = (size_t)id * 4096 + t * 4;
#pragma unroll
    for (int i = 0; i < 4; ++i) {
      const float4 v = *reinterpret_cast<const float4*>(Vf + base + i * 1024);
      u16x4 o;
      o[0] = f2bf(v.x); o[1] = f2bf(v.y); o[2] = f2bf(v.z); o[3] = f2bf(v.w);
      *reinterpret_cast<u16x4*>(Vb + base + i * 1024) = o;
    }
  }
}

// ---------------- fused flash attention: 2-stage compute pipeline
// QK(kt) overlaps SM+PV(kt-1) within each wave (MFMA pipe || VALU/TRANS pipe).
// 4-deep LDS ring (64KB), counted vmcnt(2), one barrier/iter, masks preloaded.
// 1024 blocks x 512 thr. bid: b = bid&7, qt = (bid>>3)&31, kh = bid>>8.
__global__ __launch_bounds__(512, 4) void k_attn9(const unsigned short* __restrict__ Kb,
                                                  const unsigned short* __restrict__ Vb,
                                                  const float* __restrict__ Qf,
                                                  const unsigned int* __restrict__ Bits,
                                                  float* __restrict__ Out,
                                                  float* __restrict__ Pw,
                                                  float* __restrict__ Dnp) {
  // pool: K ring 4x8K @ [0,32K) | V ring 4x8K @ [32K,64K)
  // epilogue alias: M0 [4][16][66] f32 (16896 B) | Lml [4][64] @16896
  __shared__ __align__(16) char pool[65536];

  const int bid = blockIdx.x;
  const int b = bid & 7;              // batch -> XCD (L2 locality)
  const int qt = (bid >> 3) & 31;
  const int kh = bid >> 8;            // key quarter (0..3)
  const int q0 = qt << 7;             // 128 q per block
  const int t = threadIdx.x;
  const int w = t >> 6;
  const int wq = w >> 1;              // 4 q sub-tiles of 32
  const int wk = w & 1;               // 2 key splits of 32 (within supertile)
  const int l = t & 63;
  const int l32 = l & 31;
  const int hi = l >> 5;
  const int qrow = q0 + (wq << 5) + l32;

  // ---- Q fragments (B operand of S^T = K*Q), scale folded
  bf16x8 qf[4];
  {
    const float* qb = Qf + (size_t)b * EH * NS + qrow;
#pragma unroll
    for (int eb = 0; eb < 4; ++eb)
#pragma unroll
      for (int j = 0; j < 8; ++j)
        qf[eb][j] = (short)f2bf(qb[(size_t)(16 * eb + 8 * hi + j) * NS] * SCALE_L2E);
  }

  // ---- DMA sources (pre-swizzled global, linear LDS dest); 1 chunk each
  const char* kg = (const char*)(Kb + ((size_t)b * NS + (size_t)kh * 1024) * EH) +
                   (((size_t)t * 16) ^ (size_t)(((t >> 3) & 7) << 4));
  const char* vg = (const char*)(Vb + (size_t)b * EH * NS + (size_t)kh * 1024) +
                   (size_t)(t >> 3) * (NS * 2) +
                   (size_t)((((t & 7) << 4)) ^ (((t >> 3) & 7) << 4));

  // ---- LDS read offsets (same XOR involution)
  const int R = (wk << 5) + l32;  // key row in 64-key supertile
  int koff[4];
#pragma unroll
  for (int eb = 0; eb < 4; ++eb)
    koff[eb] = (R << 7) + (((eb << 5) + (hi << 4)) ^ ((R & 7) << 4));
  int voff[2][2];
#pragma unroll
  for (int vb = 0; vb < 2; ++vb)
#pragma unroll
    for (int kb = 0; kb < 2; ++kb) {
      const int e = (vb << 5) + l32;
      voff[vb][kb] = (e << 7) + (((wk << 6) + (kb << 5) + (hi << 4)) ^ ((e & 7) << 4));
    }

  // ---- preload ALL mask words
  const unsigned int* mp = Bits + ((size_t)((kh << 5) + wk)) * NS + qrow;
  unsigned int mwv[16];
#pragma unroll
  for (int i = 0; i < 16; ++i) mwv[i] = mp[(size_t)(i * 2) * NS];

  f32x16 acc0, acc1;
#pragma unroll
  for (int r = 0; r < 16; ++r) { acc0[r] = 0.f; acc1[r] = 0.f; }
  float l_r = 0.f;

  // ---- prologue: stage tiles 0 and 1
  gl_lds16(kg, pool + t * 16);
  gl_lds16(vg, pool + 32768 + t * 16);
  gl_lds16(kg + 8192, pool + 8192 + t * 16);
  gl_lds16(vg + 128, pool + 32768 + 8192 + t * 16);

  f32x16 sp;  // s of tile kt-1 (pipeline register)

  // ---- peeled iter 0: tile 0 ready -> QK(0) only
  asm volatile("s_waitcnt vmcnt(2)" ::: "memory");
  __builtin_amdgcn_s_barrier();
  __builtin_amdgcn_sched_barrier(0);
  gl_lds16(kg + 2 * 8192, pool + 2 * 8192 + t * 16);
  gl_lds16(vg + 2 * 128, pool + 32768 + 2 * 8192 + t * 16);
  {
    const unsigned int mwh = mwv[0] >> (hi << 2);
#pragma unroll
    for (int r = 0; r < 16; ++r) {
      const int kl = (r & 3) + ((r >> 2) << 3);
      sp[r] = __int_as_float(sbfe1(mwh, kl) & 0xFF800000);
    }
    const char* Kt = pool;  // buffer 0
    const bf16x8 ka0 = *reinterpret_cast<const bf16x8*>(Kt + koff[0]);
    const bf16x8 ka1 = *reinterpret_cast<const bf16x8*>(Kt + koff[1]);
    const bf16x8 ka2 = *reinterpret_cast<const bf16x8*>(Kt + koff[2]);
    const bf16x8 ka3 = *reinterpret_cast<const bf16x8*>(Kt + koff[3]);
    __builtin_amdgcn_s_setprio(1);
    sp = __builtin_amdgcn_mfma_f32_32x32x16_bf16(ka0, qf[0], sp, 0, 0, 0);
    sp = __builtin_amdgcn_mfma_f32_32x32x16_bf16(ka1, qf[1], sp, 0, 0, 0);
    sp = __builtin_amdgcn_mfma_f32_32x32x16_bf16(ka2, qf[2], sp, 0, 0, 0);
    sp = __builtin_amdgcn_mfma_f32_32x32x16_bf16(ka3, qf[3], sp, 0, 0, 0);
    __builtin_amdgcn_s_setprio(0);
  }

#pragma unroll
  for (int kt = 1; kt < 16; ++kt) {
    // tile kt ready (tile kt+1's 2 DMAs may stay in flight)
    if (kt == 15) {
      asm volatile("s_waitcnt vmcnt(0)" ::: "memory");
    } else {
      asm volatile("s_waitcnt vmcnt(2)" ::: "memory");
    }
    __builtin_amdgcn_s_barrier();
    __builtin_amdgcn_sched_barrier(0);

    // prefetch tile kt+2 -> ring slot (kt+2)&3.
    // Overwrite-safe: that slot's last readers (K: QK in iter kt-2; V: PV in
    // iter kt-1) ran before barrier(kt), which every wave has now passed.
    if (kt < 14) {
      const int bn = (kt + 2) & 3;
      gl_lds16(kg + (size_t)(kt + 2) * 8192, pool + bn * 8192 + t * 16);
      gl_lds16(vg + (size_t)(kt + 2) * 128, pool + 32768 + bn * 8192 + t * 16);
    }

    // ---- stage 1: QK(kt) -> sc (independent MFMA work, issues first)
    f32x16 sc;
    {
      const unsigned int mwh = mwv[kt] >> (hi << 2);
#pragma unroll
      for (int r = 0; r < 16; ++r) {
        const int kl = (r & 3) + ((r >> 2) << 3);
        sc[r] = __int_as_float(sbfe1(mwh, kl) & 0xFF800000);
      }
      const char* Kt = pool + (kt & 3) * 8192;
      const bf16x8 ka0 = *reinterpret_cast<const bf16x8*>(Kt + koff[0]);
      const bf16x8 ka1 = *reinterpret_cast<const bf16x8*>(Kt + koff[1]);
      const bf16x8 ka2 = *reinterpret_cast<const bf16x8*>(Kt + koff[2]);
      const bf16x8 ka3 = *reinterpret_cast<const bf16x8*>(Kt + koff[3]);
      __builtin_amdgcn_s_setprio(1);
      sc = __builtin_amdgcn_mfma_f32_32x32x16_bf16(ka0, qf[0], sc, 0, 0, 0);
      sc = __builtin_amdgcn_mfma_f32_32x32x16_bf16(ka1, qf[1], sc, 0, 0, 0);
      sc = __builtin_amdgcn_mfma_f32_32x32x16_bf16(ka2, qf[2], sc, 0, 0, 0);
      sc = __builtin_amdgcn_mfma_f32_32x32x16_bf16(ka3, qf[3], sc, 0, 0, 0);
      __builtin_amdgcn_s_setprio(0);
    }

    // ---- stage 2: SM + PV for sp = tile kt-1 (overlaps the QK MFMAs above)
    {
#pragma unroll
      for (int r = 0; r < 16; ++r) sp[r] = fexp2(sp[r]);
      const f32x2 t0 = (f32x2){sp[0], sp[1]} + (f32x2){sp[2], sp[3]};
      const f32x2 t1 = (f32x2){sp[4], sp[5]} + (f32x2){sp[6], sp[7]};
      const f32x2 t2 = (f32x2){sp[8], sp[9]} + (f32x2){sp[10], sp[11]};
      const f32x2 t3 = (f32x2){sp[12], sp[13]} + (f32x2){sp[14], sp[15]};
      const f32x2 u = (t0 + t1) + (t2 + t3);
      l_r += u[0] + u[1];

      const char* Vt = pool + 32768 + ((kt - 1) & 3) * 8192;
      const bf16x8 va00 = *reinterpret_cast<const bf16x8*>(Vt + voff[0][0]);
      const bf16x8 va01 = *reinterpret_cast<const bf16x8*>(Vt + voff[1][0]);
      const bf16x8 va10 = *reinterpret_cast<const bf16x8*>(Vt + voff[0][1]);
      const bf16x8 va11 = *reinterpret_cast<const bf16x8*>(Vt + voff[1][1]);
#pragma unroll
      for (int kb = 0; kb < 2; ++kb) {
        const unsigned int wA0 = cvtpk(sp[8 * kb + 0], sp[8 * kb + 1]);
        const unsigned int wA1 = cvtpk(sp[8 * kb + 2], sp[8 * kb + 3]);
        const unsigned int wB0 = cvtpk(sp[8 * kb + 4], sp[8 * kb + 5]);
        const unsigned int wB1 = cvtpk(sp[8 * kb + 6], sp[8 * kb + 7]);
        const u32x2 p02 = __builtin_amdgcn_permlane32_swap(wA0, wB0, false, false);
        const u32x2 p13 = __builtin_amdgcn_permlane32_swap(wA1, wB1, false, false);
        u32x4 pw;
        pw[0] = p02[0];
        pw[1] = p13[0];
        pw[2] = p02[1];
        pw[3] = p13[1];
        const bf16x8 pfrag = __builtin_bit_cast(bf16x8, pw);
        __builtin_amdgcn_s_setprio(1);
        acc0 = __builtin_amdgcn_mfma_f32_32x32x16_bf16(kb ? va10 : va00, pfrag, acc0, 0, 0, 0);
        acc1 = __builtin_amdgcn_mfma_f32_32x32x16_bf16(kb ? va11 : va01, pfrag, acc1, 0, 0, 0);
        __builtin_amdgcn_s_setprio(0);
      }
    }

    sp = sc;  // full unroll -> SSA rename, no copy
  }

  // ---- drain: SM + PV for tile 15 (V ring slot 3)
  {
#pragma unroll
    for (int r = 0; r < 16; ++r) sp[r] = fexp2(sp[r]);
    const f32x2 t0 = (f32x2){sp[0], sp[1]} + (f32x2){sp[2], sp[3]};
    const f32x2 t1 = (f32x2){sp[4], sp[5]} + (f32x2){sp[6], sp[7]};
    const f32x2 t2 = (f32x2){sp[8], sp[9]} + (f32x2){sp[10], sp[11]};
    const f32x2 t3 = (f32x2){sp[12], sp[13]} + (f32x2){sp[14], sp[15]};
    const f32x2 u = (t0 + t1) + (t2 + t3);
    l_r += u[0] + u[1];

    const char* Vt = pool + 32768 + 3 * 8192;
    const bf16x8 va00 = *reinterpret_cast<const bf16x8*>(Vt + voff[0][0]);
    const bf16x8 va01 = *reinterpret_cast<const bf16x8*>(Vt + voff[1][0]);
    const bf16x8 va10 = *reinterpret_cast<const bf16x8*>(Vt + voff[0][1]);
    const bf16x8 va11 = *reinterpret_cast<const bf16x8*>(Vt + voff[1][1]);
#pragma unroll
    for (int kb = 0; kb < 2; ++kb) {
      const unsigned int wA0 = cvtpk(sp[8 * kb + 0], sp[8 * kb + 1]);
      const unsigned int wA1 = cvtpk(sp[8 * kb + 2], sp[8 * kb + 3]);
      const unsigned int wB0 = cvtpk(sp[8 * kb + 4], sp[8 * kb + 5]);
      const unsigned int wB1 = cvtpk(sp[8 * kb + 6], sp[8 * kb + 7]);
      const u32x2 p02 = __builtin_amdgcn_permlane32_swap(wA0, wB0, false, false);
      const u32x2 p13 = __builtin_amdgcn_permlane32_swap(wA1, wB1, false, false);
      u32x4 pw;
      pw[0] = p02[0];
      pw[1] = p13[0];
      pw[2] = p02[1];
      pw[3] = p13[1];
      const bf16x8 pfrag = __builtin_bit_cast(bf16x8, pw);
      __builtin_amdgcn_s_setprio(1);
      acc0 = __builtin_amdgcn_mfma_f32_32x32x16_bf16(kb ? va10 : va00, pfrag, acc0, 0, 0, 0);
      acc1 = __builtin_amdgcn_mfma_f32_32x32x16_bf16(kb ? va11 : va01, pfrag, acc1, 0, 0, 0);
      __builtin_amdgcn_s_setprio(0);
    }
  }

  // ---- finalize denom across lane halves
  l_r = xsum32(l_r);

  __syncthreads();  // all waves done with loop before epilogue aliases the pool

  // ---- in-block wk-pair merge (two phases), write unnormalized result
  float* M0 = reinterpret_cast<float*>(pool);           // [4][16][66]
  float* Lml = reinterpret_cast<float*>(pool + 16896);  // [4][64]
  float* Dn = Dnp + ((size_t)((qt << 3) + b) * 4 + kh) * 128;
  float* pbase;
  size_t vstride;
  if (kh == 0) {
    pbase = Out + (size_t)b * EH * NS + (qt << 7);
    vstride = NS;
  } else {
    pbase = Pw + ((size_t)((qt << 3) + b) * 3 + (kh - 1)) * 8192;
    vstride = 128;
  }

  // phase A: acc0 + denom
  if (wk == 1) {
    float* A = M0 + (size_t)wq * 16 * 66;
#pragma unroll
    for (int r = 0; r < 16; ++r) A[r * 66 + l] = acc0[r];
    Lml[wq * 64 + l] = l_r;
  }
  __syncthreads();
  if (wk == 0) {
    const float L = l_r + Lml[wq * 64 + l];
    if (hi == 0) Dn[(wq << 5) + l32] = L;
    const float* A = M0 + (size_t)wq * 16 * 66;
#pragma unroll
    for (int r = 0; r < 16; ++r) {
      const int v0 = (r & 3) + ((r >> 2) << 3) + (hi << 2);
      pbase[(size_t)v0 * vstride + (wq << 5) + l32] = acc0[r] + A[r * 66 + l];
    }
  }
  __syncthreads();
  // phase B: acc1
  if (wk == 1) {
    float* A = M0 + (size_t)wq * 16 * 66;
#pragma unroll
    for (int r = 0; r < 16; ++r) A[r * 66 + l] = acc1[r];
  }
  __syncthreads();
  if (wk == 0) {
    const float* A = M0 + (size_t)wq * 16 * 66;
#pragma unroll
    for (int r = 0; r < 16; ++r) {
      const int v0 = (r & 3) + ((r >> 2) << 3) + (hi << 2) + 32;
      pbase[(size_t)v0 * vstride + (wq << 5) + l32] = acc1[r] + A[r * 66 + l];
    }
  }
}

// ---------------- merge the 4 key-quarters and normalize
// grid 1024: b = bid&7, qt = (bid>>3)&31, vq = bid>>8 (16 v-rows per block).
__global__ __launch_bounds__(256) void k_merge(const float* __restrict__ Pw,
                                               const float* __restrict__ Dnp,
                                               float* __restrict__ Out) {
  __shared__ float inv[128];
  const int bid = blockIdx.x;
  const int b = bid & 7;
  const int qt = (bid >> 3) & 31;
  const int vq = bid >> 8;  // 0..3
  const float* Dn = Dnp + (size_t)((qt << 3) + b) * 4 * 128;
  const int t = threadIdx.x;
  if (t < 128) inv[t] = 1.0f / (Dn[t] + Dn[128 + t] + Dn[256 + t] + Dn[384 + t]);
  __syncthreads();
  const int v = (vq << 4) + (t >> 4);  // 16 v-rows per block
  const int qc = (t & 15) << 3;        // 8 q per thread
  const float* P = Pw + (size_t)((qt << 3) + b) * 3 * 8192 + v * 128 + qc;
  float* ob = Out + ((size_t)b * EH + v) * NS + (qt << 7) + qc;
#pragma unroll
  for (int j = 0; j < 2; ++j) {
    const float4 ov = *reinterpret_cast<const float4*>(ob + 4 * j);
    const float4 p1 = *reinterpret_cast<const float4*>(P + 4 * j);
    const float4 p2 = *reinterpret_cast<const float4*>(P + 8192 + 4 * j);
    const float4 p3 = *reinterpret_cast<const float4*>(P + 16384 + 4 * j);
    const float4 iv = *reinterpret_cast<const float4*>(&inv[qc + 4 * j]);
    float4 o;
    o.x = (ov.x + p1.x + p2.x + p3.x) * iv.x;
    o.y = (ov.y + p1.y + p2.y + p3.y) * iv.y;
    o.z = (ov.z + p1.z + p2.z + p3.z) * iv.z;
    o.w = (ov.w + p1.w + p2.w + p3.w) * iv.w;
    *reinterpret_cast<float4*>(ob + 4 * j) = o;
  }
}

extern "C" void kernel_launch(void* const* d_in, const int* in_sizes, int n_in,
                              void* d_out, int out_size, void* d_ws, size_t ws_size,
                              hipStream_t stream) {
  const float* Qf = (const float*)d_in[0];
  const float* Kf = (const float*)d_in[1];
  const float* Vf = (const float*)d_in[2];
  const unsigned char* Mp = (const unsigned char*)d_in[3];
  float* Out = (float*)d_out;

  unsigned short* Kb = (unsigned short*)d_ws;                       // 4 MB
  unsigned short* Vb = Kb + (size_t)NB * NS * EH;                   // 4 MB
  unsigned int* Bits = (unsigned int*)(Vb + (size_t)NB * NS * EH);  // 2 MB
  float* Pw = (float*)((char*)d_ws + 10 * 1024 * 1024 + 1024);      // 24 MB partials (kh 1..3)
  float* Dnp = Pw + (size_t)256 * 3 * 8192;                         // 512 KB denoms

  k_pre<<<dim3(5120), 256, 0, stream>>>(Kf, Vf, Mp, Kb, Vb, Bits);
  k_attn9<<<dim3(1024), 512, 0, stream>>>(Kb, Vb, Qf, Bits, Out, Pw, Dnp);
  k_merge<<<dim3(1024), 256, 0, stream>>>(Pw, Dnp, Out);
}

// Round 19
// 83.233 us; speedup vs baseline: 1.5032x; 1.5032x over previous
//
#include <hip/hip_runtime.h>

typedef __attribute__((ext_vector_type(8))) short bf16x8;
typedef __attribute__((ext_vector_type(16))) float f32x16;
typedef __attribute__((ext_vector_type(2))) float f32x2;
typedef __attribute__((ext_vector_type(8))) unsigned short u16x8;
typedef __attribute__((ext_vector_type(4))) unsigned short u16x4;
typedef __attribute__((ext_vector_type(4))) unsigned int u32x4;
typedef __attribute__((ext_vector_type(2))) unsigned int u32x2;

#define NB 8
#define EH 64
#define NS 4096
#define SCALE_L2E 0.1803368801111204f  /* 0.125 * log2(e) */

static __device__ __forceinline__ unsigned short f2bf(float f) {
  union { float f; unsigned int u; } a;
  a.f = f;
  unsigned int u = a.u;
  unsigned int lsb = (u >> 16) & 1u;
  u += 0x7fffu + lsb;  // RNE
  return (unsigned short)(u >> 16);
}

static __device__ __forceinline__ unsigned int cvtpk(float a, float b) {
  unsigned int r;
  asm("v_cvt_pk_bf16_f32 %0, %1, %2" : "=v"(r) : "v"(a), "v"(b));
  return r;
}

// raw single-instruction exp2 WITH compiler hazard handling (R14-proven).
static __device__ __forceinline__ float fexp2(float x) {
#if __has_builtin(__builtin_amdgcn_exp2f)
  return __builtin_amdgcn_exp2f(x);
#else
  return exp2f(x);
#endif
}

// 1-bit signed bitfield extract: returns 0 or -1 (v_bfe_i32, 1 op)
static __device__ __forceinline__ int sbfe1(unsigned int v, int off) {
#if __has_builtin(__builtin_amdgcn_sbfe)
  return __builtin_amdgcn_sbfe((int)v, off, 1);
#else
  return ((int)(v << (31 - off))) >> 31;
#endif
}

// cross-half (lane ^ 32) sum via v_permlane32_swap
static __device__ __forceinline__ float xsum32(float x) {
  u32x2 r = __builtin_amdgcn_permlane32_swap(__float_as_uint(x), __float_as_uint(x), false, false);
  return __uint_as_float(r[0]) + __uint_as_float(r[1]);
}

static __device__ __forceinline__ void gl_lds16(const void* g, void* l) {
  __builtin_amdgcn_global_load_lds(
      (const __attribute__((address_space(1))) unsigned int*)g,
      (__attribute__((address_space(3))) unsigned int*)l, 16, 0, 0);
}

// ---------------- fused prepass (one launch):
//   bid <  4096 : mask (Nk,Nq) -> bit-packed (Nk/32, Nq), inline dtype detect
//   4096..4607  : K transpose (B,E,N) f32 -> (B,N,E) bf16
//   4608..5119  : V convert   (B,E,N) f32 -> bf16 (layout kept)
__global__ __launch_bounds__(256) void k_pre(const float* __restrict__ Kf,
                                             const float* __restrict__ Vf,
                                             const unsigned char* __restrict__ Mp,
                                             unsigned short* __restrict__ Kb,
                                             unsigned short* __restrict__ Vb,
                                             unsigned int* __restrict__ Bits) {
  const int bid = blockIdx.x;
  const int t = threadIdx.x;
  if (bid < 4096) {
    __shared__ unsigned char Ts[64][80];
    __shared__ int sfl;
    const int q0 = (bid & 63) << 6;
    const int ky = bid >> 6;
    const int k0 = ky << 6;
    if (t == 0) sfl = 1;
    __syncthreads();
    {
      const unsigned int w0 = reinterpret_cast<const unsigned int*>(Mp)[t];
      if (!(w0 == 0u || w0 == 1u || w0 == 0x3F800000u)) sfl = 0;  // benign race
    }
    __syncthreads();
    const int wide = sfl;
    const int r = t >> 2, cs = t & 3;
    if (!wide) {
      int4 v = *reinterpret_cast<const int4*>(Mp + (size_t)(k0 + r) * NS + q0 + cs * 16);
      *reinterpret_cast<int4*>(&Ts[r][cs * 16]) = v;
    } else {
      const unsigned int* Mw =
          reinterpret_cast<const unsigned int*>(Mp) + (size_t)(k0 + r) * NS + q0 + cs * 16;
      unsigned char tmp[16];
#pragma unroll
      for (int j = 0; j < 16; ++j) tmp[j] = (unsigned char)(Mw[j] != 0u);
      *reinterpret_cast<int4*>(&Ts[r][cs * 16]) = *reinterpret_cast<const int4*>(tmp);
    }
    __syncthreads();
    const int w = t >> 6, lane = t & 63;
#pragma unroll
    for (int i = 0; i < 16; ++i) {
      const int q = (w << 4) + i;
      unsigned long long bm = __ballot(Ts[lane][q] != 0);
      if (lane == 0) {
        Bits[(size_t)(2 * ky) * NS + q0 + q] = (unsigned int)bm;
        Bits[(size_t)(2 * ky + 1) * NS + q0 + q] = (unsigned int)(bm >> 32);
      }
    }
  } else if (bid < 4608) {
    __shared__ float T[64][69];
    const int id = bid - 4096;
    const int b = id >> 6;
    const int n0 = (id & 63) << 6;
    const float* Xb = Kf + (size_t)b * EH * NS;
    unsigned short* Yb = Kb + (size_t)b * NS * EH;
    const int er = t >> 4;
    const int n4 = (t & 15) << 2;
#pragma unroll
    for (int p = 0; p < 4; ++p) {
      const int e = er + (p << 4);
      const float4 v = *reinterpret_cast<const float4*>(Xb + (size_t)e * NS + n0 + n4);
      T[e][n4] = v.x; T[e][n4 + 1] = v.y; T[e][n4 + 2] = v.z; T[e][n4 + 3] = v.w;
    }
    __syncthreads();
    const int n = t >> 2;
    const int e0 = (t & 3) << 4;
    u16x8 o0, o1;
#pragma unroll
    for (int j = 0; j < 8; ++j) o0[j] = f2bf(T[e0 + j][n]);
#pragma unroll
    for (int j = 0; j < 8; ++j) o1[j] = f2bf(T[e0 + 8 + j][n]);
    *reinterpret_cast<u16x8*>(Yb + (size_t)(n0 + n) * EH + e0) = o0;
    *reinterpret_cast<u16x8*>(Yb + (size_t)(n0 + n) * EH + e0 + 8) = o1;
  } else {
    const int id = bid - 4608;
    const size_t base = (size_t)id * 4096 + t * 4;
#pragma unroll
    for (int i = 0; i < 4; ++i) {
      const float4 v = *reinterpret_cast<const float4*>(Vf + base + i * 1024);
      u16x4 o;
      o[0] = f2bf(v.x); o[1] = f2bf(v.y); o[2] = f2bf(v.z); o[3] = f2bf(v.w);
      *reinterpret_cast<u16x4*>(Vb + base + i * 1024) = o;
    }
  }
}

// ---------------- fused flash attention: 2-stage compute pipeline
// QK(kt) overlaps SM+PV(kt-1) within each wave (MFMA pipe || VALU/TRANS pipe).
// 4-deep LDS ring (64KB), counted vmcnt(2), one barrier/iter, masks preloaded.
// launch_bounds(512,2): ~128-VGPR budget so the ~106 live regs FIT (R18's
// (512,4) clamped to 64 and spilled -> FETCH 74MB; tripwire this round).
__global__ __launch_bounds__(512, 2) void k_attn9(const unsigned short* __restrict__ Kb,
                                                  const unsigned short* __restrict__ Vb,
                                                  const float* __restrict__ Qf,
                                                  const unsigned int* __restrict__ Bits,
                                                  float* __restrict__ Out,
                                                  float* __restrict__ Pw,
                                                  float* __restrict__ Dnp) {
  // pool: K ring 4x8K @ [0,32K) | V ring 4x8K @ [32K,64K)
  // epilogue alias: M0 [4][16][66] f32 (16896 B) | Lml [4][64] @16896
  __shared__ __align__(16) char pool[65536];

  const int bid = blockIdx.x;
  const int b = bid & 7;              // batch -> XCD (L2 locality)
  const int qt = (bid >> 3) & 31;
  const int kh = bid >> 8;            // key quarter (0..3)
  const int q0 = qt << 7;             // 128 q per block
  const int t = threadIdx.x;
  const int w = t >> 6;
  const int wq = w >> 1;              // 4 q sub-tiles of 32
  const int wk = w & 1;               // 2 key splits of 32 (within supertile)
  const int l = t & 63;
  const int l32 = l & 31;
  const int hi = l >> 5;
  const int qrow = q0 + (wq << 5) + l32;

  // ---- Q fragments (B operand of S^T = K*Q), scale folded
  bf16x8 qf[4];
  {
    const float* qb = Qf + (size_t)b * EH * NS + qrow;
#pragma unroll
    for (int eb = 0; eb < 4; ++eb)
#pragma unroll
      for (int j = 0; j < 8; ++j)
        qf[eb][j] = (short)f2bf(qb[(size_t)(16 * eb + 8 * hi + j) * NS] * SCALE_L2E);
  }

  // ---- DMA sources (pre-swizzled global, linear LDS dest); 1 chunk each
  const char* kg = (const char*)(Kb + ((size_t)b * NS + (size_t)kh * 1024) * EH) +
                   (((size_t)t * 16) ^ (size_t)(((t >> 3) & 7) << 4));
  const char* vg = (const char*)(Vb + (size_t)b * EH * NS + (size_t)kh * 1024) +
                   (size_t)(t >> 3) * (NS * 2) +
                   (size_t)((((t & 7) << 4)) ^ (((t >> 3) & 7) << 4));

  // ---- LDS read offsets (same XOR involution)
  const int R = (wk << 5) + l32;  // key row in 64-key supertile
  int koff[4];
#pragma unroll
  for (int eb = 0; eb < 4; ++eb)
    koff[eb] = (R << 7) + (((eb << 5) + (hi << 4)) ^ ((R & 7) << 4));
  int voff[2][2];
#pragma unroll
  for (int vb = 0; vb < 2; ++vb)
#pragma unroll
    for (int kb = 0; kb < 2; ++kb) {
      const int e = (vb << 5) + l32;
      voff[vb][kb] = (e << 7) + (((wk << 6) + (kb << 5) + (hi << 4)) ^ ((e & 7) << 4));
    }

  // ---- preload ALL mask words
  const unsigned int* mp = Bits + ((size_t)((kh << 5) + wk)) * NS + qrow;
  unsigned int mwv[16];
#pragma unroll
  for (int i = 0; i < 16; ++i) mwv[i] = mp[(size_t)(i * 2) * NS];

  f32x16 acc0, acc1;
#pragma unroll
  for (int r = 0; r < 16; ++r) { acc0[r] = 0.f; acc1[r] = 0.f; }
  float l_r = 0.f;

  // ---- prologue: stage tiles 0 and 1
  gl_lds16(kg, pool + t * 16);
  gl_lds16(vg, pool + 32768 + t * 16);
  gl_lds16(kg + 8192, pool + 8192 + t * 16);
  gl_lds16(vg + 128, pool + 32768 + 8192 + t * 16);

  f32x16 sp;  // s of tile kt-1 (pipeline register)

  // ---- peeled iter 0: tile 0 ready -> QK(0) only
  asm volatile("s_waitcnt vmcnt(2)" ::: "memory");
  __builtin_amdgcn_s_barrier();
  __builtin_amdgcn_sched_barrier(0);
  gl_lds16(kg + 2 * 8192, pool + 2 * 8192 + t * 16);
  gl_lds16(vg + 2 * 128, pool + 32768 + 2 * 8192 + t * 16);
  {
    const unsigned int mwh = mwv[0] >> (hi << 2);
#pragma unroll
    for (int r = 0; r < 16; ++r) {
      const int kl = (r & 3) + ((r >> 2) << 3);
      sp[r] = __int_as_float(sbfe1(mwh, kl) & 0xFF800000);
    }
    const char* Kt = pool;  // buffer 0
    const bf16x8 ka0 = *reinterpret_cast<const bf16x8*>(Kt + koff[0]);
    const bf16x8 ka1 = *reinterpret_cast<const bf16x8*>(Kt + koff[1]);
    const bf16x8 ka2 = *reinterpret_cast<const bf16x8*>(Kt + koff[2]);
    const bf16x8 ka3 = *reinterpret_cast<const bf16x8*>(Kt + koff[3]);
    __builtin_amdgcn_s_setprio(1);
    sp = __builtin_amdgcn_mfma_f32_32x32x16_bf16(ka0, qf[0], sp, 0, 0, 0);
    sp = __builtin_amdgcn_mfma_f32_32x32x16_bf16(ka1, qf[1], sp, 0, 0, 0);
    sp = __builtin_amdgcn_mfma_f32_32x32x16_bf16(ka2, qf[2], sp, 0, 0, 0);
    sp = __builtin_amdgcn_mfma_f32_32x32x16_bf16(ka3, qf[3], sp, 0, 0, 0);
    __builtin_amdgcn_s_setprio(0);
  }

#pragma unroll
  for (int kt = 1; kt < 16; ++kt) {
    // tile kt ready (tile kt+1's 2 DMAs may stay in flight)
    if (kt == 15) {
      asm volatile("s_waitcnt vmcnt(0)" ::: "memory");
    } else {
      asm volatile("s_waitcnt vmcnt(2)" ::: "memory");
    }
    __builtin_amdgcn_s_barrier();
    __builtin_amdgcn_sched_barrier(0);

    // prefetch tile kt+2 -> ring slot (kt+2)&3.
    // Overwrite-safe: that slot's last readers (K: QK in iter kt-2; V: PV in
    // iter kt-1) ran before barrier(kt), which every wave has now passed.
    if (kt < 14) {
      const int bn = (kt + 2) & 3;
      gl_lds16(kg + (size_t)(kt + 2) * 8192, pool + bn * 8192 + t * 16);
      gl_lds16(vg + (size_t)(kt + 2) * 128, pool + 32768 + bn * 8192 + t * 16);
    }

    // ---- stage 1: QK(kt) -> sc (independent MFMA work, issues first)
    f32x16 sc;
    {
      const unsigned int mwh = mwv[kt] >> (hi << 2);
#pragma unroll
      for (int r = 0; r < 16; ++r) {
        const int kl = (r & 3) + ((r >> 2) << 3);
        sc[r] = __int_as_float(sbfe1(mwh, kl) & 0xFF800000);
      }
      const char* Kt = pool + (kt & 3) * 8192;
      const bf16x8 ka0 = *reinterpret_cast<const bf16x8*>(Kt + koff[0]);
      const bf16x8 ka1 = *reinterpret_cast<const bf16x8*>(Kt + koff[1]);
      const bf16x8 ka2 = *reinterpret_cast<const bf16x8*>(Kt + koff[2]);
      const bf16x8 ka3 = *reinterpret_cast<const bf16x8*>(Kt + koff[3]);
      __builtin_amdgcn_s_setprio(1);
      sc = __builtin_amdgcn_mfma_f32_32x32x16_bf16(ka0, qf[0], sc, 0, 0, 0);
      sc = __builtin_amdgcn_mfma_f32_32x32x16_bf16(ka1, qf[1], sc, 0, 0, 0);
      sc = __builtin_amdgcn_mfma_f32_32x32x16_bf16(ka2, qf[2], sc, 0, 0, 0);
      sc = __builtin_amdgcn_mfma_f32_32x32x16_bf16(ka3, qf[3], sc, 0, 0, 0);
      __builtin_amdgcn_s_setprio(0);
    }

    // ---- stage 2: SM + PV for sp = tile kt-1 (overlaps the QK MFMAs above)
    {
#pragma unroll
      for (int r = 0; r < 16; ++r) sp[r] = fexp2(sp[r]);
      const f32x2 t0 = (f32x2){sp[0], sp[1]} + (f32x2){sp[2], sp[3]};
      const f32x2 t1 = (f32x2){sp[4], sp[5]} + (f32x2){sp[6], sp[7]};
      const f32x2 t2 = (f32x2){sp[8], sp[9]} + (f32x2){sp[10], sp[11]};
      const f32x2 t3 = (f32x2){sp[12], sp[13]} + (f32x2){sp[14], sp[15]};
      const f32x2 u = (t0 + t1) + (t2 + t3);
      l_r += u[0] + u[1];

      const char* Vt = pool + 32768 + ((kt - 1) & 3) * 8192;
      const bf16x8 va00 = *reinterpret_cast<const bf16x8*>(Vt + voff[0][0]);
      const bf16x8 va01 = *reinterpret_cast<const bf16x8*>(Vt + voff[1][0]);
      const bf16x8 va10 = *reinterpret_cast<const bf16x8*>(Vt + voff[0][1]);
      const bf16x8 va11 = *reinterpret_cast<const bf16x8*>(Vt + voff[1][1]);
#pragma unroll
      for (int kb = 0; kb < 2; ++kb) {
        const unsigned int wA0 = cvtpk(sp[8 * kb + 0], sp[8 * kb + 1]);
        const unsigned int wA1 = cvtpk(sp[8 * kb + 2], sp[8 * kb + 3]);
        const unsigned int wB0 = cvtpk(sp[8 * kb + 4], sp[8 * kb + 5]);
        const unsigned int wB1 = cvtpk(sp[8 * kb + 6], sp[8 * kb + 7]);
        const u32x2 p02 = __builtin_amdgcn_permlane32_swap(wA0, wB0, false, false);
        const u32x2 p13 = __builtin_amdgcn_permlane32_swap(wA1, wB1, false, false);
        u32x4 pw;
        pw[0] = p02[0];
        pw[1] = p13[0];
        pw[2] = p02[1];
        pw[3] = p13[1];
        const bf16x8 pfrag = __builtin_bit_cast(bf16x8, pw);
        __builtin_amdgcn_s_setprio(1);
        acc0 = __builtin_amdgcn_mfma_f32_32x32x16_bf16(kb ? va10 : va00, pfrag, acc0, 0, 0, 0);
        acc1 = __builtin_amdgcn_mfma_f32_32x32x16_bf16(kb ? va11 : va01, pfrag, acc1, 0, 0, 0);
        __builtin_amdgcn_s_setprio(0);
      }
    }

    sp = sc;  // full unroll -> SSA rename, no copy
  }

  // ---- drain: SM + PV for tile 15 (V ring slot 3)
  {
#pragma unroll
    for (int r = 0; r < 16; ++r) sp[r] = fexp2(sp[r]);
    const f32x2 t0 = (f32x2){sp[0], sp[1]} + (f32x2){sp[2], sp[3]};
    const f32x2 t1 = (f32x2){sp[4], sp[5]} + (f32x2){sp[6], sp[7]};
    const f32x2 t2 = (f32x2){sp[8], sp[9]} + (f32x2){sp[10], sp[11]};
    const f32x2 t3 = (f32x2){sp[12], sp[13]} + (f32x2){sp[14], sp[15]};
    const f32x2 u = (t0 + t1) + (t2 + t3);
    l_r += u[0] + u[1];

    const char* Vt = pool + 32768 + 3 * 8192;
    const bf16x8 va00 = *reinterpret_cast<const bf16x8*>(Vt + voff[0][0]);
    const bf16x8 va01 = *reinterpret_cast<const bf16x8*>(Vt + voff[1][0]);
    const bf16x8 va10 = *reinterpret_cast<const bf16x8*>(Vt + voff[0][1]);
    const bf16x8 va11 = *reinterpret_cast<const bf16x8*>(Vt + voff[1][1]);
#pragma unroll
    for (int kb = 0; kb < 2; ++kb) {
      const unsigned int wA0 = cvtpk(sp[8 * kb + 0], sp[8 * kb + 1]);
      const unsigned int wA1 = cvtpk(sp[8 * kb + 2], sp[8 * kb + 3]);
      const unsigned int wB0 = cvtpk(sp[8 * kb + 4], sp[8 * kb + 5]);
      const unsigned int wB1 = cvtpk(sp[8 * kb + 6], sp[8 * kb + 7]);
      const u32x2 p02 = __builtin_amdgcn_permlane32_swap(wA0, wB0, false, false);
      const u32x2 p13 = __builtin_amdgcn_permlane32_swap(wA1, wB1, false, false);
      u32x4 pw;
      pw[0] = p02[0];
      pw[1] = p13[0];
      pw[2] = p02[1];
      pw[3] = p13[1];
      const bf16x8 pfrag = __builtin_bit_cast(bf16x8, pw);
      __builtin_amdgcn_s_setprio(1);
      acc0 = __builtin_amdgcn_mfma_f32_32x32x16_bf16(kb ? va10 : va00, pfrag, acc0, 0, 0, 0);
      acc1 = __builtin_amdgcn_mfma_f32_32x32x16_bf16(kb ? va11 : va01, pfrag, acc1, 0, 0, 0);
      __builtin_amdgcn_s_setprio(0);
    }
  }

  // ---- finalize denom across lane halves
  l_r = xsum32(l_r);

  __syncthreads();  // all waves done with loop before epilogue aliases the pool

  // ---- in-block wk-pair merge (two phases), write unnormalized result
  float* M0 = reinterpret_cast<float*>(pool);           // [4][16][66]
  float* Lml = reinterpret_cast<float*>(pool + 16896);  // [4][64]
  float* Dn = Dnp + ((size_t)((qt << 3) + b) * 4 + kh) * 128;
  float* pbase;
  size_t vstride;
  if (kh == 0) {
    pbase = Out + (size_t)b * EH * NS + (qt << 7);
    vstride = NS;
  } else {
    pbase = Pw + ((size_t)((qt << 3) + b) * 3 + (kh - 1)) * 8192;
    vstride = 128;
  }

  // phase A: acc0 + denom
  if (wk == 1) {
    float* A = M0 + (size_t)wq * 16 * 66;
#pragma unroll
    for (int r = 0; r < 16; ++r) A[r * 66 + l] = acc0[r];
    Lml[wq * 64 + l] = l_r;
  }
  __syncthreads();
  if (wk == 0) {
    const float L = l_r + Lml[wq * 64 + l];
    if (hi == 0) Dn[(wq << 5) + l32] = L;
    const float* A = M0 + (size_t)wq * 16 * 66;
#pragma unroll
    for (int r = 0; r < 16; ++r) {
      const int v0 = (r & 3) + ((r >> 2) << 3) + (hi << 2);
      pbase[(size_t)v0 * vstride + (wq << 5) + l32] = acc0[r] + A[r * 66 + l];
    }
  }
  __syncthreads();
  // phase B: acc1
  if (wk == 1) {
    float* A = M0 + (size_t)wq * 16 * 66;
#pragma unroll
    for (int r = 0; r < 16; ++r) A[r * 66 + l] = acc1[r];
  }
  __syncthreads();
  if (wk == 0) {
    const float* A = M0 + (size_t)wq * 16 * 66;
#pragma unroll
    for (int r = 0; r < 16; ++r) {
      const int v0 = (r & 3) + ((r >> 2) << 3) + (hi << 2) + 32;
      pbase[(size_t)v0 * vstride + (wq << 5) + l32] = acc1[r] + A[r * 66 + l];
    }
  }
}

// ---------------- merge the 4 key-quarters and normalize
// grid 1024: b = bid&7, qt = (bid>>3)&31, vq = bid>>8 (16 v-rows per block).
__global__ __launch_bounds__(256) void k_merge(const float* __restrict__ Pw,
                                               const float* __restrict__ Dnp,
                                               float* __restrict__ Out) {
  __shared__ float inv[128];
  const int bid = blockIdx.x;
  const int b = bid & 7;
  const int qt = (bid >> 3) & 31;
  const int vq = bid >> 8;  // 0..3
  const float* Dn = Dnp + (size_t)((qt << 3) + b) * 4 * 128;
  const int t = threadIdx.x;
  if (t < 128) inv[t] = 1.0f / (Dn[t] + Dn[128 + t] + Dn[256 + t] + Dn[384 + t]);
  __syncthreads();
  const int v = (vq << 4) + (t >> 4);  // 16 v-rows per block
  const int qc = (t & 15) << 3;        // 8 q per thread
  const float* P = Pw + (size_t)((qt << 3) + b) * 3 * 8192 + v * 128 + qc;
  float* ob = Out + ((size_t)b * EH + v) * NS + (qt << 7) + qc;
#pragma unroll
  for (int j = 0; j < 2; ++j) {
    const float4 ov = *reinterpret_cast<const float4*>(ob + 4 * j);
    const float4 p1 = *reinterpret_cast<const float4*>(P + 4 * j);
    const float4 p2 = *reinterpret_cast<const float4*>(P + 8192 + 4 * j);
    const float4 p3 = *reinterpret_cast<const float4*>(P + 16384 + 4 * j);
    const float4 iv = *reinterpret_cast<const float4*>(&inv[qc + 4 * j]);
    float4 o;
    o.x = (ov.x + p1.x + p2.x + p3.x) * iv.x;
    o.y = (ov.y + p1.y + p2.y + p3.y) * iv.y;
    o.z = (ov.z + p1.z + p2.z + p3.z) * iv.z;
    o.w = (ov.w + p1.w + p2.w + p3.w) * iv.w;
    *reinterpret_cast<float4*>(ob + 4 * j) = o;
  }
}

extern "C" void kernel_launch(void* const* d_in, const int* in_sizes, int n_in,
                              void* d_out, int out_size, void* d_ws, size_t ws_size,
                              hipStream_t stream) {
  const float* Qf = (const float*)d_in[0];
  const float* Kf = (const float*)d_in[1];
  const float* Vf = (const float*)d_in[2];
  const unsigned char* Mp = (const unsigned char*)d_in[3];
  float* Out = (float*)d_out;

  unsigned short* Kb = (unsigned short*)d_ws;                       // 4 MB
  unsigned short* Vb = Kb + (size_t)NB * NS * EH;                   // 4 MB
  unsigned int* Bits = (unsigned int*)(Vb + (size_t)NB * NS * EH);  // 2 MB
  float* Pw = (float*)((char*)d_ws + 10 * 1024 * 1024 + 1024);      // 24 MB partials (kh 1..3)
  float* Dnp = Pw + (size_t)256 * 3 * 8192;                         // 512 KB denoms

  k_pre<<<dim3(5120), 256, 0, stream>>>(Kf, Vf, Mp, Kb, Vb, Bits);
  k_attn9<<<dim3(1024), 512, 0, stream>>>(Kb, Vb, Qf, Bits, Out, Pw, Dnp);
  k_merge<<<dim3(1024), 256, 0, stream>>>(Pw, Dnp, Out);
}

// Round 20
// 74.273 us; speedup vs baseline: 1.6845x; 1.1206x over previous
//
#include <hip/hip_runtime.h>

typedef __attribute__((ext_vector_type(8))) short bf16x8;
typedef __attribute__((ext_vector_type(16))) float f32x16;
typedef __attribute__((ext_vector_type(2))) float f32x2;
typedef __attribute__((ext_vector_type(8))) unsigned short u16x8;
typedef __attribute__((ext_vector_type(4))) unsigned short u16x4;
typedef __attribute__((ext_vector_type(4))) unsigned int u32x4;
typedef __attribute__((ext_vector_type(2))) unsigned int u32x2;

#define NB 8
#define EH 64
#define NS 4096
#define SCALE_L2E 0.1803368801111204f  /* 0.125 * log2(e) */

static __device__ __forceinline__ unsigned short f2bf(float f) {
  union { float f; unsigned int u; } a;
  a.f = f;
  unsigned int u = a.u;
  unsigned int lsb = (u >> 16) & 1u;
  u += 0x7fffu + lsb;  // RNE
  return (unsigned short)(u >> 16);
}

static __device__ __forceinline__ unsigned int cvtpk(float a, float b) {
  unsigned int r;
  asm("v_cvt_pk_bf16_f32 %0, %1, %2" : "=v"(r) : "v"(a), "v"(b));
  return r;
}

// raw single-instruction exp2 WITH compiler hazard handling (R14-proven).
static __device__ __forceinline__ float fexp2(float x) {
#if __has_builtin(__builtin_amdgcn_exp2f)
  return __builtin_amdgcn_exp2f(x);
#else
  return exp2f(x);
#endif
}

// 1-bit signed bitfield extract: returns 0 or -1 (v_bfe_i32, 1 op)
static __device__ __forceinline__ int sbfe1(unsigned int v, int off) {
#if __has_builtin(__builtin_amdgcn_sbfe)
  return __builtin_amdgcn_sbfe((int)v, off, 1);
#else
  return ((int)(v << (31 - off))) >> 31;
#endif
}

// cross-half (lane ^ 32) sum via v_permlane32_swap
static __device__ __forceinline__ float xsum32(float x) {
  u32x2 r = __builtin_amdgcn_permlane32_swap(__float_as_uint(x), __float_as_uint(x), false, false);
  return __uint_as_float(r[0]) + __uint_as_float(r[1]);
}

static __device__ __forceinline__ void gl_lds16(const void* g, void* l) {
  __builtin_amdgcn_global_load_lds(
      (const __attribute__((address_space(1))) unsigned int*)g,
      (__attribute__((address_space(3))) unsigned int*)l, 16, 0, 0);
}

// ---------------- fused prepass (one launch):
//   bid <  4096 : mask (Nk,Nq) -> bit-packed (Nk/32, Nq), inline dtype detect
//   4096..4607  : K transpose (B,E,N) f32 -> (B,N,E) bf16
//   4608..5119  : V convert   (B,E,N) f32 -> bf16 (layout kept)
__global__ __launch_bounds__(256) void k_pre(const float* __restrict__ Kf,
                                             const float* __restrict__ Vf,
                                             const unsigned char* __restrict__ Mp,
                                             unsigned short* __restrict__ Kb,
                                             unsigned short* __restrict__ Vb,
                                             unsigned int* __restrict__ Bits) {
  const int bid = blockIdx.x;
  const int t = threadIdx.x;
  if (bid < 4096) {
    __shared__ unsigned char Ts[64][80];
    __shared__ int sfl;
    const int q0 = (bid & 63) << 6;
    const int ky = bid >> 6;
    const int k0 = ky << 6;
    if (t == 0) sfl = 1;
    __syncthreads();
    {
      const unsigned int w0 = reinterpret_cast<const unsigned int*>(Mp)[t];
      if (!(w0 == 0u || w0 == 1u || w0 == 0x3F800000u)) sfl = 0;  // benign race
    }
    __syncthreads();
    const int wide = sfl;
    const int r = t >> 2, cs = t & 3;
    if (!wide) {
      int4 v = *reinterpret_cast<const int4*>(Mp + (size_t)(k0 + r) * NS + q0 + cs * 16);
      *reinterpret_cast<int4*>(&Ts[r][cs * 16]) = v;
    } else {
      const unsigned int* Mw =
          reinterpret_cast<const unsigned int*>(Mp) + (size_t)(k0 + r) * NS + q0 + cs * 16;
      unsigned char tmp[16];
#pragma unroll
      for (int j = 0; j < 16; ++j) tmp[j] = (unsigned char)(Mw[j] != 0u);
      *reinterpret_cast<int4*>(&Ts[r][cs * 16]) = *reinterpret_cast<const int4*>(tmp);
    }
    __syncthreads();
    const int w = t >> 6, lane = t & 63;
#pragma unroll
    for (int i = 0; i < 16; ++i) {
      const int q = (w << 4) + i;
      unsigned long long bm = __ballot(Ts[lane][q] != 0);
      if (lane == 0) {
        Bits[(size_t)(2 * ky) * NS + q0 + q] = (unsigned int)bm;
        Bits[(size_t)(2 * ky + 1) * NS + q0 + q] = (unsigned int)(bm >> 32);
      }
    }
  } else if (bid < 4608) {
    __shared__ float T[64][69];
    const int id = bid - 4096;
    const int b = id >> 6;
    const int n0 = (id & 63) << 6;
    const float* Xb = Kf + (size_t)b * EH * NS;
    unsigned short* Yb = Kb + (size_t)b * NS * EH;
    const int er = t >> 4;
    const int n4 = (t & 15) << 2;
#pragma unroll
    for (int p = 0; p < 4; ++p) {
      const int e = er + (p << 4);
      const float4 v = *reinterpret_cast<const float4*>(Xb + (size_t)e * NS + n0 + n4);
      T[e][n4] = v.x; T[e][n4 + 1] = v.y; T[e][n4 + 2] = v.z; T[e][n4 + 3] = v.w;
    }
    __syncthreads();
    const int n = t >> 2;
    const int e0 = (t & 3) << 4;
    u16x8 o0, o1;
#pragma unroll
    for (int j = 0; j < 8; ++j) o0[j] = f2bf(T[e0 + j][n]);
#pragma unroll
    for (int j = 0; j < 8; ++j) o1[j] = f2bf(T[e0 + 8 + j][n]);
    *reinterpret_cast<u16x8*>(Yb + (size_t)(n0 + n) * EH + e0) = o0;
    *reinterpret_cast<u16x8*>(Yb + (size_t)(n0 + n) * EH + e0 + 8) = o1;
  } else {
    const int id = bid - 4608;
    const size_t base = (size_t)id * 4096 + t * 4;
#pragma unroll
    for (int i = 0; i < 4; ++i) {
      const float4 v = *reinterpret_cast<const float4*>(Vf + base + i * 1024);
      u16x4 o;
      o[0] = f2bf(v.x); o[1] = f2bf(v.y); o[2] = f2bf(v.z); o[3] = f2bf(v.w);
      *reinterpret_cast<u16x4*>(Vb + base + i * 1024) = o;
    }
  }
}

// ---------------- fused flash attention: counted-vmcnt triple-buffer pipeline
// (R17 configuration: best measured — attn ~54.5 us)
// 1024 blocks x 512 thr x 48KB LDS. bid: b = bid&7, qt = (bid>>3)&31 (128 q),
// kh = bid>>8 (1024 keys, 16 iters). 8 waves = wq4 x wk2. 64-key supertiles,
// prefetch distance 2, ONE barrier/iter, vmcnt(2) (never 0 in steady state).
__global__ __launch_bounds__(512, 4) void k_attn9(const unsigned short* __restrict__ Kb,
                                                  const unsigned short* __restrict__ Vb,
                                                  const float* __restrict__ Qf,
                                                  const unsigned int* __restrict__ Bits,
                                                  float* __restrict__ Out,
                                                  float* __restrict__ Pw,
                                                  float* __restrict__ Dnp) {
  // pool: K bufs 0..2 @ [0,24K), V bufs 0..2 @ [24K,48K)
  // epilogue alias: M0 [4][16][66] f32 (16896 B) | Lml [4][64] @16896
  __shared__ __align__(16) char pool[49152];

  const int bid = blockIdx.x;
  const int b = bid & 7;              // batch -> XCD (L2 locality)
  const int qt = (bid >> 3) & 31;
  const int kh = bid >> 8;            // key quarter (0..3)
  const int q0 = qt << 7;             // 128 q per block
  const int t = threadIdx.x;
  const int w = t >> 6;
  const int wq = w >> 1;              // 4 q sub-tiles of 32
  const int wk = w & 1;               // 2 key splits of 32 (within supertile)
  const int l = t & 63;
  const int l32 = l & 31;
  const int hi = l >> 5;
  const int qrow = q0 + (wq << 5) + l32;

  // ---- Q fragments (B operand of S^T = K*Q), scale folded
  bf16x8 qf[4];
  {
    const float* qb = Qf + (size_t)b * EH * NS + qrow;
#pragma unroll
    for (int eb = 0; eb < 4; ++eb)
#pragma unroll
      for (int j = 0; j < 8; ++j)
        qf[eb][j] = (short)f2bf(qb[(size_t)(16 * eb + 8 * hi + j) * NS] * SCALE_L2E);
  }

  // ---- DMA sources (pre-swizzled global, linear LDS dest); 1 chunk each
  const char* kg = (const char*)(Kb + ((size_t)b * NS + (size_t)kh * 1024) * EH) +
                   (((size_t)t * 16) ^ (size_t)(((t >> 3) & 7) << 4));
  const char* vg = (const char*)(Vb + (size_t)b * EH * NS + (size_t)kh * 1024) +
                   (size_t)(t >> 3) * (NS * 2) +
                   (size_t)((((t & 7) << 4)) ^ (((t >> 3) & 7) << 4));

  // ---- LDS read offsets (same XOR involution)
  const int R = (wk << 5) + l32;  // key row in 64-key supertile
  int koff[4];
#pragma unroll
  for (int eb = 0; eb < 4; ++eb)
    koff[eb] = (R << 7) + (((eb << 5) + (hi << 4)) ^ ((R & 7) << 4));
  int voff[2][2];
#pragma unroll
  for (int vb = 0; vb < 2; ++vb)
#pragma unroll
    for (int kb = 0; kb < 2; ++kb) {
      const int e = (vb << 5) + l32;
      voff[vb][kb] = (e << 7) + (((wk << 6) + (kb << 5) + (hi << 4)) ^ ((e & 7) << 4));
    }

  // ---- preload ALL mask words (removes the vmcnt(0)-forcing per-iter load)
  const unsigned int* mp = Bits + ((size_t)((kh << 5) + wk)) * NS + qrow;
  unsigned int mwv[16];
#pragma unroll
  for (int i = 0; i < 16; ++i) mwv[i] = mp[(size_t)(i * 2) * NS];

  f32x16 acc0, acc1;
#pragma unroll
  for (int r = 0; r < 16; ++r) { acc0[r] = 0.f; acc1[r] = 0.f; }
  float l_r = 0.f;

  // ---- prologue: stage supertiles 0 and 1
  gl_lds16(kg, pool + t * 16);
  gl_lds16(vg, pool + 24576 + t * 16);
  gl_lds16(kg + 8192, pool + 8192 + t * 16);
  gl_lds16(vg + 128, pool + 24576 + 8192 + t * 16);

#pragma unroll
  for (int kt = 0; kt < 16; ++kt) {
    // counted wait: own DMA(kt) retired (only DMA(kt+1) may stay in flight),
    // then barrier globalizes "tile kt fully staged" across waves.
    if (kt == 15) {
      asm volatile("s_waitcnt vmcnt(0)" ::: "memory");
    } else {
      asm volatile("s_waitcnt vmcnt(2)" ::: "memory");
    }
    __builtin_amdgcn_s_barrier();
    __builtin_amdgcn_sched_barrier(0);

    // prefetch tile kt+2 (issued AFTER the barrier -> overwrite-safe: any wave
    // issuing DMA(kt+2) has passed barrier(kt), so all reads of buffer
    // (kt+2)%3 == (kt-1)%3 finished in iter kt-1)
    if (kt < 14) {
      const int bn = (kt + 2) % 3;
      gl_lds16(kg + (size_t)(kt + 2) * 8192, pool + bn * 8192 + t * 16);
      gl_lds16(vg + (size_t)(kt + 2) * 128, pool + 24576 + bn * 8192 + t * 16);
    }

    const int bc = kt % 3;
    const char* Kt = pool + bc * 8192;
    const char* Vt = pool + 24576 + bc * 8192;

    // ---- S^T init = mask (C-operand): masked -> -inf, 2 ops/elem (bfe+and)
    const unsigned int mwh = mwv[kt] >> (hi << 2);
    f32x16 s;
#pragma unroll
    for (int r = 0; r < 16; ++r) {
      const int kl = (r & 3) + ((r >> 2) << 3);  // compile-time per r
      s[r] = __int_as_float(sbfe1(mwh, kl) & 0xFF800000);
    }

    // ---- S^T[k][q]
    const bf16x8 ka0 = *reinterpret_cast<const bf16x8*>(Kt + koff[0]);
    const bf16x8 ka1 = *reinterpret_cast<const bf16x8*>(Kt + koff[1]);
    const bf16x8 ka2 = *reinterpret_cast<const bf16x8*>(Kt + koff[2]);
    const bf16x8 ka3 = *reinterpret_cast<const bf16x8*>(Kt + koff[3]);
    __builtin_amdgcn_s_setprio(1);
    s = __builtin_amdgcn_mfma_f32_32x32x16_bf16(ka0, qf[0], s, 0, 0, 0);
    s = __builtin_amdgcn_mfma_f32_32x32x16_bf16(ka1, qf[1], s, 0, 0, 0);
    s = __builtin_amdgcn_mfma_f32_32x32x16_bf16(ka2, qf[2], s, 0, 0, 0);
    s = __builtin_amdgcn_mfma_f32_32x32x16_bf16(ka3, qf[3], s, 0, 0, 0);
    __builtin_amdgcn_s_setprio(0);

    // ---- p = 2^s: single v_exp_f32/elem (args >= -30 or -inf; exp2(-inf)=0)
#pragma unroll
    for (int r = 0; r < 16; ++r) s[r] = fexp2(s[r]);

    // ---- denominator: packed f32x2 tree + deferred cross-half
    {
      const f32x2 t0 = (f32x2){s[0], s[1]} + (f32x2){s[2], s[3]};
      const f32x2 t1 = (f32x2){s[4], s[5]} + (f32x2){s[6], s[7]};
      const f32x2 t2 = (f32x2){s[8], s[9]} + (f32x2){s[10], s[11]};
      const f32x2 t3 = (f32x2){s[12], s[13]} + (f32x2){s[14], s[15]};
      const f32x2 u = (t0 + t1) + (t2 + t3);
      l_r += u[0] + u[1];
    }

    // ---- PV: cvt_pk -> permlane32_swap -> MFMAs
    const bf16x8 va00 = *reinterpret_cast<const bf16x8*>(Vt + voff[0][0]);
    const bf16x8 va01 = *reinterpret_cast<const bf16x8*>(Vt + voff[1][0]);
    const bf16x8 va10 = *reinterpret_cast<const bf16x8*>(Vt + voff[0][1]);
    const bf16x8 va11 = *reinterpret_cast<const bf16x8*>(Vt + voff[1][1]);
#pragma unroll
    for (int kb = 0; kb < 2; ++kb) {
      const unsigned int wA0 = cvtpk(s[8 * kb + 0], s[8 * kb + 1]);
      const unsigned int wA1 = cvtpk(s[8 * kb + 2], s[8 * kb + 3]);
      const unsigned int wB0 = cvtpk(s[8 * kb + 4], s[8 * kb + 5]);
      const unsigned int wB1 = cvtpk(s[8 * kb + 6], s[8 * kb + 7]);
      const u32x2 p02 = __builtin_amdgcn_permlane32_swap(wA0, wB0, false, false);
      const u32x2 p13 = __builtin_amdgcn_permlane32_swap(wA1, wB1, false, false);
      u32x4 pw;
      pw[0] = p02[0];
      pw[1] = p13[0];
      pw[2] = p02[1];
      pw[3] = p13[1];
      const bf16x8 pfrag = __builtin_bit_cast(bf16x8, pw);
      __builtin_amdgcn_s_setprio(1);
      acc0 = __builtin_amdgcn_mfma_f32_32x32x16_bf16(kb ? va10 : va00, pfrag, acc0, 0, 0, 0);
      acc1 = __builtin_amdgcn_mfma_f32_32x32x16_bf16(kb ? va11 : va01, pfrag, acc1, 0, 0, 0);
      __builtin_amdgcn_s_setprio(0);
    }
  }

  // ---- finalize denom across lane halves (deferred from loop)
  l_r = xsum32(l_r);

  __syncthreads();  // all waves done with loop before epilogue aliases the pool

  // ---- in-block wk-pair merge (two phases), write unnormalized result
  float* M0 = reinterpret_cast<float*>(pool);           // [4][16][66]
  float* Lml = reinterpret_cast<float*>(pool + 16896);  // [4][64]
  float* Dn = Dnp + ((size_t)((qt << 3) + b) * 4 + kh) * 128;
  float* pbase;
  size_t vstride;
  if (kh == 0) {
    pbase = Out + (size_t)b * EH * NS + (qt << 7);
    vstride = NS;
  } else {
    pbase = Pw + ((size_t)((qt << 3) + b) * 3 + (kh - 1)) * 8192;
    vstride = 128;
  }

  // phase A: acc0 + denom
  if (wk == 1) {
    float* A = M0 + (size_t)wq * 16 * 66;
#pragma unroll
    for (int r = 0; r < 16; ++r) A[r * 66 + l] = acc0[r];
    Lml[wq * 64 + l] = l_r;
  }
  __syncthreads();
  if (wk == 0) {
    const float L = l_r + Lml[wq * 64 + l];
    if (hi == 0) Dn[(wq << 5) + l32] = L;
    const float* A = M0 + (size_t)wq * 16 * 66;
#pragma unroll
    for (int r = 0; r < 16; ++r) {
      const int v0 = (r & 3) + ((r >> 2) << 3) + (hi << 2);
      pbase[(size_t)v0 * vstride + (wq << 5) + l32] = acc0[r] + A[r * 66 + l];
    }
  }
  __syncthreads();
  // phase B: acc1
  if (wk == 1) {
    float* A = M0 + (size_t)wq * 16 * 66;
#pragma unroll
    for (int r = 0; r < 16; ++r) A[r * 66 + l] = acc1[r];
  }
  __syncthreads();
  if (wk == 0) {
    const float* A = M0 + (size_t)wq * 16 * 66;
#pragma unroll
    for (int r = 0; r < 16; ++r) {
      const int v0 = (r & 3) + ((r >> 2) << 3) + (hi << 2) + 32;
      pbase[(size_t)v0 * vstride + (wq << 5) + l32] = acc1[r] + A[r * 66 + l];
    }
  }
}

// ---------------- merge the 4 key-quarters and normalize
// grid 1024: b = bid&7, qt = (bid>>3)&31, vq = bid>>8 (16 v-rows per block).
__global__ __launch_bounds__(256) void k_merge(const float* __restrict__ Pw,
                                               const float* __restrict__ Dnp,
                                               float* __restrict__ Out) {
  __shared__ float inv[128];
  const int bid = blockIdx.x;
  const int b = bid & 7;
  const int qt = (bid >> 3) & 31;
  const int vq = bid >> 8;  // 0..3
  const float* Dn = Dnp + (size_t)((qt << 3) + b) * 4 * 128;
  const int t = threadIdx.x;
  if (t < 128) inv[t] = 1.0f / (Dn[t] + Dn[128 + t] + Dn[256 + t] + Dn[384 + t]);
  __syncthreads();
  const int v = (vq << 4) + (t >> 4);  // 16 v-rows per block
  const int qc = (t & 15) << 3;        // 8 q per thread
  const float* P = Pw + (size_t)((qt << 3) + b) * 3 * 8192 + v * 128 + qc;
  float* ob = Out + ((size_t)b * EH + v) * NS + (qt << 7) + qc;
#pragma unroll
  for (int j = 0; j < 2; ++j) {
    const float4 ov = *reinterpret_cast<const float4*>(ob + 4 * j);
    const float4 p1 = *reinterpret_cast<const float4*>(P + 4 * j);
    const float4 p2 = *reinterpret_cast<const float4*>(P + 8192 + 4 * j);
    const float4 p3 = *reinterpret_cast<const float4*>(P + 16384 + 4 * j);
    const float4 iv = *reinterpret_cast<const float4*>(&inv[qc + 4 * j]);
    float4 o;
    o.x = (ov.x + p1.x + p2.x + p3.x) * iv.x;
    o.y = (ov.y + p1.y + p2.y + p3.y) * iv.y;
    o.z = (ov.z + p1.z + p2.z + p3.z) * iv.z;
    o.w = (ov.w + p1.w + p2.w + p3.w) * iv.w;
    *reinterpret_cast<float4*>(ob + 4 * j) = o;
  }
}

extern "C" void kernel_launch(void* const* d_in, const int* in_sizes, int n_in,
                              void* d_out, int out_size, void* d_ws, size_t ws_size,
                              hipStream_t stream) {
  const float* Qf = (const float*)d_in[0];
  const float* Kf = (const float*)d_in[1];
  const float* Vf = (const float*)d_in[2];
  const unsigned char* Mp = (const unsigned char*)d_in[3];
  float* Out = (float*)d_out;

  unsigned short* Kb = (unsigned short*)d_ws;                       // 4 MB
  unsigned short* Vb = Kb + (size_t)NB * NS * EH;                   // 4 MB
  unsigned int* Bits = (unsigned int*)(Vb + (size_t)NB * NS * EH);  // 2 MB
  float* Pw = (float*)((char*)d_ws + 10 * 1024 * 1024 + 1024);      // 24 MB partials (kh 1..3)
  float* Dnp = Pw + (size_t)256 * 3 * 8192;                         // 512 KB denoms

  k_pre<<<dim3(5120), 256, 0, stream>>>(Kf, Vf, Mp, Kb, Vb, Bits);
  k_attn9<<<dim3(1024), 512, 0, stream>>>(Kb, Vb, Qf, Bits, Out, Pw, Dnp);
  k_merge<<<dim3(1024), 256, 0, stream>>>(Pw, Dnp, Out);
}